// Round 15
// baseline (2408.015 us; speedup 1.0000x reference)
//
#include <hip/hip_runtime.h>
#include <hip/hip_bf16.h>

typedef unsigned short u16;
typedef __attribute__((ext_vector_type(4))) float f32x4;
typedef __attribute__((ext_vector_type(8))) __bf16 bf16x8;

#define DEV static __device__ __forceinline__

// ---------- helpers ----------
DEV float b2f(u16 v) { return __uint_as_float(((unsigned)v) << 16); }

DEV u16 f2b(float f) {  // round-to-nearest-even f32 -> bf16 bits
  unsigned u = __float_as_uint(f);
  return (u16)((u + 0x7fffu + ((u >> 16) & 1u)) >> 16);
}

DEV unsigned pk2(float a, float b) {
  return (unsigned)f2b(a) | ((unsigned)f2b(b) << 16);
}

DEV void gload16(const void* g, void* l) {
  // async global->LDS, 16B per lane; LDS dest is wave-uniform base + lane*16
  __builtin_amdgcn_global_load_lds(
      (__attribute__((address_space(1))) void*)g,
      (__attribute__((address_space(3))) void*)l, 16, 0, 0);
}

DEV float wave_sum(float v) {
  #pragma unroll
  for (int o = 32; o; o >>= 1) v += __shfl_xor(v, o, 64);
  return v;
}

// ---------- embeddings + LayerNorm (bf16 out) ----------
__global__ __launch_bounds__(256)
void embed_ln_k(const int* __restrict__ ids, const int* __restrict__ tts,
                const float* __restrict__ we, const float* __restrict__ pe,
                const float* __restrict__ te, const float* __restrict__ g,
                const float* __restrict__ bb, u16* __restrict__ x) {
  const int t = blockIdx.x;          // 0..4095 token index
  const int pos = t & 511;
  const int tid = threadIdx.x, lane = tid & 63, w = tid >> 6;
  const int id = ids[t], tt = tts[t];
  __shared__ float red[8];
  float e[3];
  #pragma unroll
  for (int k = 0; k < 3; k++) {
    int d = tid + k * 256;
    e[k] = we[(size_t)id * 768 + d] + pe[(size_t)pos * 768 + d] + te[(size_t)tt * 768 + d];
  }
  float s = wave_sum(e[0] + e[1] + e[2]);
  if (lane == 0) red[w] = s;
  __syncthreads();
  const float mean = (red[0] + red[1] + red[2] + red[3]) * (1.f / 768.f);
  float v2 = 0.f;
  #pragma unroll
  for (int k = 0; k < 3; k++) { float d = e[k] - mean; v2 += d * d; }
  v2 = wave_sum(v2);
  if (lane == 0) red[4 + w] = v2;
  __syncthreads();
  const float var = (red[4] + red[5] + red[6] + red[7]) * (1.f / 768.f);
  const float rstd = rsqrtf(var + 1e-5f);
  #pragma unroll
  for (int k = 0; k < 3; k++) {
    int d = tid + k * 256;
    x[(size_t)t * 768 + d] = f2b((e[k] - mean) * rstd * g[d] + bb[d]);
  }
}

// ---------- LayerNorm bf16 -> bf16, wave-per-token (no LDS, no barriers) ----------
// grid 1024 blocks x 256 threads = 4096 tokens; uint2 loads (4 bf16), f32 stats.
__global__ __launch_bounds__(256)
void ln_k(const u16* __restrict__ xin, const float* __restrict__ g,
          const float* __restrict__ bb, u16* __restrict__ out) {
  const int lane = threadIdx.x & 63, w = threadIdx.x >> 6;
  const int t = blockIdx.x * 4 + w;
  const uint2* x2 = (const uint2*)(xin + (size_t)t * 768);
  float e[12];
  #pragma unroll
  for (int k = 0; k < 3; k++) {
    uint2 v = x2[k * 64 + lane];
    e[k * 4 + 0] = b2f((u16)v.x);
    e[k * 4 + 1] = b2f((u16)(v.x >> 16));
    e[k * 4 + 2] = b2f((u16)v.y);
    e[k * 4 + 3] = b2f((u16)(v.y >> 16));
  }
  float s = 0.f;
  #pragma unroll
  for (int i = 0; i < 12; i++) s += e[i];
  s = wave_sum(s);
  const float mean = s * (1.f / 768.f);
  float v2 = 0.f;
  #pragma unroll
  for (int i = 0; i < 12; i++) { float d = e[i] - mean; v2 += d * d; }
  v2 = wave_sum(v2);
  const float rstd = rsqrtf(v2 * (1.f / 768.f) + 1e-5f);
  uint2* o2 = (uint2*)(out + (size_t)t * 768);
  #pragma unroll
  for (int k = 0; k < 3; k++) {
    float4 gv = ((const float4*)g)[k * 64 + lane];
    float4 bv = ((const float4*)bb)[k * 64 + lane];
    uint2 o;
    o.x = pk2((e[k * 4 + 0] - mean) * rstd * gv.x + bv.x,
              (e[k * 4 + 1] - mean) * rstd * gv.y + bv.y);
    o.y = pk2((e[k * 4 + 2] - mean) * rstd * gv.z + bv.z,
              (e[k * 4 + 3] - mean) * rstd * gv.w + bv.w);
    o2[k * 64 + lane] = o;
  }
}

// ---------- word_emb f32[30522,768] -> bf16[30592,768], pad rows zeroed ----------
__global__ __launch_bounds__(256)
void wecast_k(const float* __restrict__ we, u16* __restrict__ out) {
  const int i = blockIdx.x * 256 + threadIdx.x;  // 8-elem chunk, 2,936,832 total
  const int row = i / 96, c8 = i % 96;
  uint2 o0 = make_uint2(0u, 0u), o1 = make_uint2(0u, 0u);
  if (row < 30522) {
    const float* src = we + (size_t)row * 768 + c8 * 8;
    float4 a = ((const float4*)src)[0];
    float4 b = ((const float4*)src)[1];
    o0.x = pk2(a.x, a.y); o0.y = pk2(a.z, a.w);
    o1.x = pk2(b.x, b.y); o1.y = pk2(b.z, b.w);
  }
  uint2* dst = (uint2*)(out + (size_t)i * 8);
  dst[0] = o0;
  dst[1] = o1;
}

// ---------- transpose-convert tile body: W f32[K,N] 64x64 tile -> Wt bf16[N,K] ----------
DEV void tconv_tile(const float* __restrict__ W, u16* __restrict__ Wt,
                    int K, int N, int n0, int k0, int tid, u16 (*t)[65]) {
  const int kl = tid >> 4, nl4 = (tid & 15) * 4;
  #pragma unroll
  for (int i = 0; i < 4; i++) {
    float4 v = *(const float4*)(W + (size_t)(k0 + kl + i * 16) * N + n0 + nl4);
    t[nl4 + 0][kl + i * 16] = f2b(v.x);
    t[nl4 + 1][kl + i * 16] = f2b(v.y);
    t[nl4 + 2][kl + i * 16] = f2b(v.z);
    t[nl4 + 3][kl + i * 16] = f2b(v.w);
  }
  __syncthreads();
  const int nl = tid >> 2, kc = (tid & 3) * 16;
  unsigned wd[8];
  #pragma unroll
  for (int j = 0; j < 8; j++)
    wd[j] = (unsigned)t[nl][kc + 2 * j] | ((unsigned)t[nl][kc + 2 * j + 1] << 16);
  int4* dst = (int4*)(Wt + (size_t)(n0 + nl) * K + k0 + kc);
  dst[0] = make_int4((int)wd[0], (int)wd[1], (int)wd[2], (int)wd[3]);
  dst[1] = make_int4((int)wd[4], (int)wd[5], (int)wd[6], (int)wd[7]);
}

// per-layer fallback kernel: grid (N/64, K/64)
__global__ __launch_bounds__(256)
void tconv_k(const float* __restrict__ W, u16* __restrict__ Wt, int K, int N) {
  __shared__ u16 t[64][65];
  tconv_tile(W, Wt, K, N, blockIdx.x * 64, blockIdx.y * 64, threadIdx.x, t);
}

// all layers, all 4 weight matrices, one launch. 1728 tiles/layer x 12.
__global__ __launch_bounds__(256)
void tconv_all_k(const float* __restrict__ wqkv, const float* __restrict__ wprj,
                 const float* __restrict__ wfc, const float* __restrict__ wfc2,
                 u16* __restrict__ wall) {
  __shared__ u16 ts[64][65];
  const int tile = blockIdx.x;
  const int l = tile / 1728, t = tile % 1728;
  u16* base = wall + (size_t)l * 7077888;
  const float* W; u16* Wt; int K, N, loc;
  if (t < 432)       { W = wqkv + (size_t)l * 768 * 2304; Wt = base;           K = 768;  N = 2304; loc = t; }
  else if (t < 576)  { W = wprj + (size_t)l * 768 * 768;  Wt = base + 1769472; K = 768;  N = 768;  loc = t - 432; }
  else if (t < 1152) { W = wfc  + (size_t)l * 768 * 3072; Wt = base + 2359296; K = 768;  N = 3072; loc = t - 576; }
  else               { W = wfc2 + (size_t)l * 3072 * 768; Wt = base + 4718592; K = 3072; N = 768;  loc = t - 1152; }
  const int nbl = N >> 6;
  tconv_tile(W, Wt, K, N, (loc % nbl) * 64, (loc / nbl) * 64, threadIdx.x, ts);
}

// ---------- GEMM 128x128 (proven best): BK=64, single-buffered ----------
// LDS tiles [row][64] (128B rows) XOR-swizzled: 16B slot s of row r holds
// global slot s^(r&7); staged via pre-swizzled global_load_lds source ->
// conflict-free ds_read_b128. XCD-chunk swizzle, N-fastest decode.
// EPI: 0 = bf16; 1 = GELU -> bf16; 2 = resid_bf16 + v -> bf16.
template <int EPI>
__global__ __launch_bounds__(256)
void gemm_k(const u16* __restrict__ A, const u16* __restrict__ B,
            const float* __restrict__ bias, const u16* __restrict__ resid,
            void* __restrict__ Cptr, int Ndim, int Kdim, int Nblk) {
  __shared__ __align__(16) u16 As[128 * 64];
  __shared__ __align__(16) u16 Bs[128 * 64];
  const int tid = threadIdx.x, lane = tid & 63, w = tid >> 6;
  const int wr = w >> 1, wc = w & 1, fr = lane & 15, fq = lane >> 4;

  const int nwg = gridDim.x, chunk = nwg >> 3;
  const int tile = (blockIdx.x & 7) * chunk + (blockIdx.x >> 3);
  const int nb = tile % Nblk, mb = tile / Nblk;
  const int n0 = nb * 128, m0 = mb * 128;

  f32x4 acc[4][4] = {};
  const int rl = lane >> 3;                 // row-in-group 0..7
  const int sl = ((lane & 7) ^ rl) * 8;     // pre-swizzled k-slot (u16 units)

  for (int k0 = 0; k0 < Kdim; k0 += 64) {
    #pragma unroll
    for (int i = 0; i < 4; i++) {
      const int row = i * 32 + w * 8 + rl;
      gload16(A + (size_t)(m0 + row) * Kdim + k0 + sl, As + (i * 32 + w * 8) * 64);
      gload16(B + (size_t)(n0 + row) * Kdim + k0 + sl, Bs + (i * 32 + w * 8) * 64);
    }
    __syncthreads();
    #pragma unroll
    for (int kh = 0; kh < 2; kh++) {
      const int ks = ((kh * 4 + fq) ^ (fr & 7)) * 8;
      bf16x8 af[4], bfv[4];
      #pragma unroll
      for (int m = 0; m < 4; m++)
        af[m] = *(const bf16x8*)(&As[(wr * 64 + m * 16 + fr) * 64 + ks]);
      #pragma unroll
      for (int n = 0; n < 4; n++)
        bfv[n] = *(const bf16x8*)(&Bs[(wc * 64 + n * 16 + fr) * 64 + ks]);
      #pragma unroll
      for (int m = 0; m < 4; m++)
        #pragma unroll
        for (int n = 0; n < 4; n++)
          acc[m][n] = __builtin_amdgcn_mfma_f32_16x16x32_bf16(af[m], bfv[n], acc[m][n], 0, 0, 0);
    }
    __syncthreads();
  }

  #pragma unroll
  for (int m = 0; m < 4; m++) {
    const int row = m0 + wr * 64 + m * 16 + fq * 4;
    #pragma unroll
    for (int n = 0; n < 4; n++) {
      const int col = n0 + wc * 64 + n * 16 + fr;
      const float bv = (bias != nullptr) ? bias[col] : 0.f;
      #pragma unroll
      for (int r = 0; r < 4; r++) {
        float v = acc[m][n][r] + bv;
        const size_t idx = (size_t)(row + r) * Ndim + col;
        if (EPI == 0) {
          ((u16*)Cptr)[idx] = f2b(v);
        } else if (EPI == 1) {
          float t = v;
          float gl = 0.5f * t * (1.f + tanhf(0.7978845608f * (t + 0.044715f * t * t * t)));
          ((u16*)Cptr)[idx] = f2b(gl);
        } else if (EPI == 2) {
          ((u16*)Cptr)[idx] = f2b(b2f(resid[idx]) + v);
        }
      }
    }
  }
}

// ---------- GEMM 64x64 (proj, fc2; proven best): BK=64, single-buffered ----------
template <int EPI>
__global__ __launch_bounds__(256)
void gemm64_k(const u16* __restrict__ A, const u16* __restrict__ B,
              const float* __restrict__ bias, const u16* __restrict__ resid,
              void* __restrict__ Cptr, int Ndim, int Kdim, int Nblk) {
  __shared__ __align__(16) u16 As[64 * 64];
  __shared__ __align__(16) u16 Bs[64 * 64];
  const int tid = threadIdx.x, lane = tid & 63, w = tid >> 6;
  const int wr = w >> 1, wc = w & 1, fr = lane & 15, fq = lane >> 4;

  const int nwg = gridDim.x, chunk = nwg >> 3;
  const int tile = (blockIdx.x & 7) * chunk + (blockIdx.x >> 3);
  const int nb = tile % Nblk, mb = tile / Nblk;
  const int n0 = nb * 64, m0 = mb * 64;

  f32x4 acc[2][2] = {};
  const int rl = lane >> 3;
  const int sl = ((lane & 7) ^ rl) * 8;

  for (int k0 = 0; k0 < Kdim; k0 += 64) {
    #pragma unroll
    for (int i = 0; i < 2; i++) {
      const int row = i * 32 + w * 8 + rl;
      gload16(A + (size_t)(m0 + row) * Kdim + k0 + sl, As + (i * 32 + w * 8) * 64);
      gload16(B + (size_t)(n0 + row) * Kdim + k0 + sl, Bs + (i * 32 + w * 8) * 64);
    }
    __syncthreads();
    #pragma unroll
    for (int kh = 0; kh < 2; kh++) {
      const int ks = ((kh * 4 + fq) ^ (fr & 7)) * 8;
      bf16x8 af[2], bfv[2];
      #pragma unroll
      for (int m = 0; m < 2; m++)
        af[m] = *(const bf16x8*)(&As[(wr * 32 + m * 16 + fr) * 64 + ks]);
      #pragma unroll
      for (int n = 0; n < 2; n++)
        bfv[n] = *(const bf16x8*)(&Bs[(wc * 32 + n * 16 + fr) * 64 + ks]);
      #pragma unroll
      for (int m = 0; m < 2; m++)
        #pragma unroll
        for (int n = 0; n < 2; n++)
          acc[m][n] = __builtin_amdgcn_mfma_f32_16x16x32_bf16(af[m], bfv[n], acc[m][n], 0, 0, 0);
    }
    __syncthreads();
  }

  #pragma unroll
  for (int m = 0; m < 2; m++) {
    const int row = m0 + wr * 32 + m * 16 + fq * 4;
    #pragma unroll
    for (int n = 0; n < 2; n++) {
      const int col = n0 + wc * 32 + n * 16 + fr;
      const float bv = (bias != nullptr) ? bias[col] : 0.f;
      #pragma unroll
      for (int r = 0; r < 4; r++) {
        float v = acc[m][n][r] + bv;
        const size_t idx = (size_t)(row + r) * Ndim + col;
        if (EPI == 0) {
          ((u16*)Cptr)[idx] = f2b(v);
        } else if (EPI == 1) {
          float t = v;
          float gl = 0.5f * t * (1.f + tanhf(0.7978845608f * (t + 0.044715f * t * t * t)));
          ((u16*)Cptr)[idx] = f2b(gl);
        } else if (EPI == 2) {
          ((u16*)Cptr)[idx] = f2b(b2f(resid[idx]) + v);
        }
      }
    }
  }
}

// ---------- GEMM 256x128 (logits): BK=32 dbuf + counted vmcnt (T4) ----------
// Pipeline per K-tile: STAGE(next, 6 loads/wave) -> s_waitcnt vmcnt(6)
// (current tile's 6 loads done; next 6 stay in flight) -> s_barrier ->
// compute (32 MFMA/wave) -> s_barrier. Never drains vmcnt to 0 mid-loop.
// Output stored NON-TEMPORALLY: d_out (500 MB f32) is never re-read, and its
// write stream was flushing B (47 MB word_emb) out of L2/L3 -> every XCD
// re-fetched B from HBM (FETCH 382 MB = 8x47.7). nt stores keep B cache-
// resident so its loads become L2/L3 hits the vmcnt(6) prefetch fully covers.
// Swizzle: LDS slot s of row r holds global slot s^((r>>1)&3) -> conflict-free.
__global__ __launch_bounds__(256)
void gemm256_k(const u16* __restrict__ A, const u16* __restrict__ B,
               float* __restrict__ Cptr, int Ndim, int Kdim, int Nblk) {
  __shared__ __align__(16) u16 As[2][256 * 32];  // 2 x 16 KB
  __shared__ __align__(16) u16 Bs[2][128 * 32];  // 2 x 8 KB
  const int tid = threadIdx.x, lane = tid & 63, w = tid >> 6;
  const int fr = lane & 15, fq = lane >> 4;

  const int nwg = gridDim.x, chunk = nwg >> 3;
  const int tile = (blockIdx.x & 7) * chunk + (blockIdx.x >> 3);
  const int nb = tile % Nblk, mb = tile / Nblk;
  const int n0 = nb * 128, m0 = mb * 256;

  f32x4 acc[4][8] = {};
  const int rq = lane >> 2;                          // row within 16-row stripe
  const int sl = ((lane & 3) ^ ((lane >> 3) & 3)) * 8;

  #define STAGE256(k0, buf)                                                     \
    {                                                                           \
      _Pragma("unroll")                                                         \
      for (int i = 0; i < 4; i++) {                                             \
        const int st = i * 4 + w;                                               \
        gload16(A + (size_t)(m0 + st * 16 + rq) * Kdim + (k0) + sl,             \
                &As[buf][st * 512]);                                            \
      }                                                                         \
      _Pragma("unroll")                                                         \
      for (int i = 0; i < 2; i++) {                                             \
        const int st = i * 4 + w;                                               \
        gload16(B + (size_t)(n0 + st * 16 + rq) * Kdim + (k0) + sl,             \
                &Bs[buf][st * 512]);                                            \
      }                                                                         \
    }

  STAGE256(0, 0);
  int buf = 0;
  const int nt = Kdim >> 5;

  for (int t = 0; t < nt; ++t) {
    if (t + 1 < nt) {
      STAGE256((t + 1) * 32, buf ^ 1);
      asm volatile("s_waitcnt vmcnt(6)" ::: "memory");
    } else {
      asm volatile("s_waitcnt vmcnt(0)" ::: "memory");
    }
    __builtin_amdgcn_s_barrier();
    __builtin_amdgcn_sched_barrier(0);

    const int ks = (fq ^ ((fr >> 1) & 3)) * 8;
    bf16x8 af[4], bfv[8];
    #pragma unroll
    for (int m = 0; m < 4; m++)
      af[m] = *(const bf16x8*)(&As[buf][(w * 64 + m * 16 + fr) * 32 + ks]);
    #pragma unroll
    for (int n = 0; n < 8; n++)
      bfv[n] = *(const bf16x8*)(&Bs[buf][(n * 16 + fr) * 32 + ks]);
    #pragma unroll
    for (int m = 0; m < 4; m++)
      #pragma unroll
      for (int n = 0; n < 8; n++)
        acc[m][n] = __builtin_amdgcn_mfma_f32_16x16x32_bf16(af[m], bfv[n], acc[m][n], 0, 0, 0);

    __builtin_amdgcn_sched_barrier(0);
    __builtin_amdgcn_s_barrier();
    buf ^= 1;
  }
  #undef STAGE256

  #pragma unroll
  for (int m = 0; m < 4; m++) {
    const int row = m0 + w * 64 + m * 16 + fq * 4;
    #pragma unroll
    for (int n = 0; n < 8; n++) {
      const int col = n0 + n * 16 + fr;
      if (col >= Ndim) continue;
      #pragma unroll
      for (int r = 0; r < 4; r++)
        __builtin_nontemporal_store(acc[m][n][r],
                                    &Cptr[(size_t)(row + r) * Ndim + col]);
    }
  }
}

// ---------- MFMA flash attention, swapped-QK^T lane-local softmax ----------
__global__ __launch_bounds__(256)
void attn_mfma_k(const u16* __restrict__ qkv, const float* __restrict__ amask,
                 u16* __restrict__ y) {
  __shared__ __align__(16) u16 Ks[2][64 * 64];   // [key][dim]  16 KB
  __shared__ __align__(16) u16 Vt[2][64 * 64];   // [dim][key]  16 KB
  __shared__ __align__(16) u16 Ps[4][16 * 64];   // per-wave P^T[q][key] 8 KB
  __shared__ float bias_lds[512];                // (1-mask)*-1e4  2 KB
  const int tid = threadIdx.x, lane = tid & 63, w = tid >> 6;
  const int bh = blockIdx.y, b = bh / 12, hh = bh % 12;
  const int q0 = blockIdx.x * 64;
  const u16* qb = qkv + (size_t)(b * 512) * 2304 + hh * 64;
  const u16* kb = qb + 768;
  const u16* vb = qb + 1536;
  const int fr = lane & 15, fq = lane >> 4;

  // mask bias -> LDS once
  bias_lds[tid] = (1.0f - amask[b * 512 + tid]) * -10000.0f;
  bias_lds[tid + 256] = (1.0f - amask[b * 512 + tid + 256]) * -10000.0f;

  // Q fragments (B-operand: lane fr -> q col fr)
  bf16x8 af[2];
  {
    const u16* qrow = qb + (size_t)(q0 + w * 16 + fr) * 2304;
    af[0] = *(const bf16x8*)(qrow + fq * 8);
    af[1] = *(const bf16x8*)(qrow + 32 + fq * 8);
  }

  auto stageK = [&](int kt, int nb) {
    const int r0 = lane >> 3, dc = lane & 7, s = dc ^ r0;
    #pragma unroll
    for (int p = 0; p < 2; p++) {
      const int i = w * 2 + p;
      gload16(kb + (size_t)(kt * 64 + i * 8 + r0) * 2304 + s * 8,
              (void*)&Ks[nb][i * 512]);
    }
  };
  auto stageV = [&](int kt, int nb) {
    #pragma unroll
    for (int p = 0; p < 2; p++) {
      const int dc = w * 2 + p;
      int4 vd = *(const int4*)(vb + (size_t)(kt * 64 + lane) * 2304 + dc * 8);
      union { int4 v; u16 e[8]; } u; u.v = vd;
      #pragma unroll
      for (int ii = 0; ii < 8; ii++)
        Vt[nb][(dc * 8 + ii) * 64 + (lane ^ (ii << 3))] = u.e[ii];
    }
  };

  f32x4 O[4];   // O^T: lane holds O[d = nd*16 + fq*4 + r][q = fr]
  #pragma unroll
  for (int nd = 0; nd < 4; nd++) O[nd] = f32x4{0.f, 0.f, 0.f, 0.f};
  float run_m = -3.0e38f, run_l = 0.f;

  stageK(0, 0); stageV(0, 0);
  __syncthreads();
  int cur = 0;

  for (int kt = 0; kt < 8; kt++) {
    if (kt < 7) { stageK(kt + 1, cur ^ 1); stageV(kt + 1, cur ^ 1); }

    // ---- QK^T swapped: sacc[n] = mfma(K-frag as A, Q-frag as B) ----
    f32x4 sacc[4];
    #pragma unroll
    for (int n = 0; n < 4; n++) sacc[n] = f32x4{0.f, 0.f, 0.f, 0.f};
    __builtin_amdgcn_s_setprio(1);
    #pragma unroll
    for (int n = 0; n < 4; n++)
      #pragma unroll
      for (int kh = 0; kh < 2; kh++) {
        bf16x8 kf = *(const bf16x8*)(&Ks[cur][(n * 16 + fr) * 64 + ((kh * 4 + fq) ^ (fr & 7)) * 8]);
        sacc[n] = __builtin_amdgcn_mfma_f32_16x16x32_bf16(kf, af[kh], sacc[n], 0, 0, 0);
      }
    __builtin_amdgcn_s_setprio(0);

    // ---- lane-local softmax: 16 scores for q=fr (keys n*16+fq*4+r) ----
    float s[4][4];
    float vm = -3.0e38f;
    #pragma unroll
    for (int n = 0; n < 4; n++) {
      float4 b4 = *(const float4*)(&bias_lds[kt * 64 + n * 16 + fq * 4]);
      s[n][0] = sacc[n][0] * 0.125f + b4.x;
      s[n][1] = sacc[n][1] * 0.125f + b4.y;
      s[n][2] = sacc[n][2] * 0.125f + b4.z;
      s[n][3] = sacc[n][3] * 0.125f + b4.w;
      vm = fmaxf(vm, fmaxf(fmaxf(s[n][0], s[n][1]), fmaxf(s[n][2], s[n][3])));
    }
    vm = fmaxf(vm, __shfl_xor(vm, 16, 64));
    vm = fmaxf(vm, __shfl_xor(vm, 32, 64));
    const float nm = fmaxf(run_m, vm);
    const float al = __expf(run_m - nm);
    run_m = nm;
    float p[4][4], ts = 0.f;
    #pragma unroll
    for (int n = 0; n < 4; n++)
      #pragma unroll
      for (int r = 0; r < 4; r++) { p[n][r] = __expf(s[n][r] - nm); ts += p[n][r]; }
    ts += __shfl_xor(ts, 16, 64);
    ts += __shfl_xor(ts, 32, 64);
    run_l = run_l * al + ts;
    #pragma unroll
    for (int nd = 0; nd < 4; nd++) O[nd] *= al;

    // ---- P^T[q=fr][key] -> Ps (swizzled 16B slots within 128B rows) ----
    #pragma unroll
    for (int n = 0; n < 4; n++) {
      uint2 dw;
      dw.x = pk2(p[n][0], p[n][1]);
      dw.y = pk2(p[n][2], p[n][3]);
      const int slot = (2 * n + (fq >> 1)) ^ (fr & 7);
      *(uint2*)((char*)&Ps[w][0] + fr * 128 + slot * 16 + (fq & 1) * 8) = dw;
    }
    asm volatile("s_waitcnt lgkmcnt(0)" ::: "memory");
    __builtin_amdgcn_sched_barrier(0);

    // ---- PV: O^T[d][q] += V^T-frag (A, rows=d) x P^T-frag (B, cols=q) ----
    bf16x8 pb[2];
    #pragma unroll
    for (int kh = 0; kh < 2; kh++)
      pb[kh] = *(const bf16x8*)((char*)&Ps[w][0] + fr * 128 + (((kh * 4 + fq) ^ (fr & 7)) * 16));
    __builtin_amdgcn_s_setprio(1);
    #pragma unroll
    for (int nd = 0; nd < 4; nd++) {
      bf16x8 vf0 = *(const bf16x8*)(&Vt[cur][(nd * 16 + fr) * 64 + ((0 + fq) ^ (fr & 7)) * 8]);
      bf16x8 vf1 = *(const bf16x8*)(&Vt[cur][(nd * 16 + fr) * 64 + ((4 + fq) ^ (fr & 7)) * 8]);
      O[nd] = __builtin_amdgcn_mfma_f32_16x16x32_bf16(vf0, pb[0], O[nd], 0, 0, 0);
      O[nd] = __builtin_amdgcn_mfma_f32_16x16x32_bf16(vf1, pb[1], O[nd], 0, 0, 0);
    }
    __builtin_amdgcn_s_setprio(0);
    __syncthreads();
    cur ^= 1;
  }

  // ---- epilogue: lane writes q=fr row, d = nd*16 + fq*4 + {0..3} packed ----
  const float inv = 1.0f / run_l;
  u16* yrow = y + (size_t)(b * 512 + q0 + w * 16 + fr) * 768 + hh * 64;
  #pragma unroll
  for (int nd = 0; nd < 4; nd++) {
    uint2 o;
    o.x = pk2(O[nd][0] * inv, O[nd][1] * inv);
    o.y = pk2(O[nd][2] * inv, O[nd][3] * inv);
    *(uint2*)(yrow + nd * 16 + fq * 4) = o;
  }
}

// ---------- launch ----------
extern "C" void kernel_launch(void* const* d_in, const int* in_sizes, int n_in,
                              void* d_out, int out_size, void* d_ws, size_t ws_size,
                              hipStream_t stream) {
  (void)in_sizes; (void)n_in; (void)out_size;
  const int*   ids  = (const int*)d_in[0];
  const int*   tts  = (const int*)d_in[1];
  const float* am   = (const float*)d_in[2];
  const float* we   = (const float*)d_in[3];
  const float* pe   = (const float*)d_in[4];
  const float* te   = (const float*)d_in[5];
  const float* eg   = (const float*)d_in[6];
  const float* eb   = (const float*)d_in[7];
  const float* l1g  = (const float*)d_in[8];
  const float* l1b  = (const float*)d_in[9];
  const float* wqkv = (const float*)d_in[10];
  const float* bqkv = (const float*)d_in[11];
  const float* wprj = (const float*)d_in[12];
  const float* bprj = (const float*)d_in[13];
  const float* l2g  = (const float*)d_in[14];
  const float* l2b  = (const float*)d_in[15];
  const float* wfc  = (const float*)d_in[16];
  const float* bfc  = (const float*)d_in[17];
  const float* wfc2 = (const float*)d_in[18];
  const float* bfc2 = (const float*)d_in[19];

  char* ws = (char*)d_ws;
  u16*  x    = (u16*)ws;                        //  6,291,456 B  residual stream bf16
  u16*  h    = (u16*)(ws + 6291456);            //  6,291,456 B  LN output bf16
  u16*  qkv  = (u16*)(ws + 12582912);           // 18,874,368 B
  u16*  y    = (u16*)(ws + 31457280);           //  6,291,456 B
  u16*  fc   = (u16*)(ws + 12582912);           // aliases qkv+y (dead by then)
  u16*  we_b = (u16*)(ws + 37748736);           // 46,989,312 B  [30592,768] zero-padded
  u16*  wall = (u16*)(ws + 84738048);           // upfront: 169,869,312 B (12 x 14,155,776)
  // upfront total: 254,607,360 B; fallback total: 98,893,824 B
  const bool upfront = ws_size >= 254607360ull;
  // fallback per-layer staging buffers live where wall starts
  u16* wqkv_f = (u16*)(ws + 84738048);
  u16* wprj_f = wqkv_f + 1769472;
  u16* wfc_f  = wqkv_f + 2359296;
  u16* wfc2_f = wqkv_f + 4718592;

  wecast_k<<<11472, 256, 0, stream>>>(we, we_b);
  embed_ln_k<<<4096, 256, 0, stream>>>(ids, tts, we, pe, te, eg, eb, x);
  if (upfront)
    tconv_all_k<<<20736, 256, 0, stream>>>(wqkv, wprj, wfc, wfc2, wall);

  for (int l = 0; l < 12; l++) {
    u16 *wq_b, *wp_b, *wf_b, *w2_b;
    if (upfront) {
      u16* base = wall + (size_t)l * 7077888;
      wq_b = base; wp_b = base + 1769472; wf_b = base + 2359296; w2_b = base + 4718592;
    } else {
      tconv_k<<<dim3(36, 12), 256, 0, stream>>>(wqkv + (size_t)l * 768 * 2304, wqkv_f, 768, 2304);
      tconv_k<<<dim3(12, 12), 256, 0, stream>>>(wprj + (size_t)l * 768 * 768,  wprj_f, 768, 768);
      tconv_k<<<dim3(48, 12), 256, 0, stream>>>(wfc  + (size_t)l * 768 * 3072, wfc_f,  768, 3072);
      tconv_k<<<dim3(12, 48), 256, 0, stream>>>(wfc2 + (size_t)l * 3072 * 768, wfc2_f, 3072, 768);
      wq_b = wqkv_f; wp_b = wprj_f; wf_b = wfc_f; w2_b = wfc2_f;
    }

    ln_k<<<1024, 256, 0, stream>>>(x, l1g + l * 768, l1b + l * 768, h);
    gemm_k<0><<<576, 256, 0, stream>>>(
        h, wq_b, bqkv + l * 2304, nullptr, qkv, 2304, 768, 18);
    attn_mfma_k<<<dim3(8, 96), 256, 0, stream>>>(qkv, am, y);
    gemm64_k<2><<<768, 256, 0, stream>>>(
        y, wp_b, bprj + l * 768, x, x, 768, 768, 12);
    ln_k<<<1024, 256, 0, stream>>>(x, l2g + l * 768, l2b + l * 768, h);
    gemm_k<1><<<768, 256, 0, stream>>>(
        h, wf_b, bfc + l * 3072, nullptr, fc, 3072, 768, 24);
    gemm64_k<2><<<768, 256, 0, stream>>>(
        fc, w2_b, bfc2 + l * 768, x, x, 768, 3072, 12);
  }

  gemm256_k<<<3824, 256, 0, stream>>>(
      x, we_b, (float*)d_out, 30522, 768, 239);
}

// Round 16
// 2234.049 us; speedup vs baseline: 1.0779x; 1.0779x over previous
//
#include <hip/hip_runtime.h>
#include <hip/hip_bf16.h>

typedef unsigned short u16;
typedef __attribute__((ext_vector_type(4))) float f32x4;
typedef __attribute__((ext_vector_type(8))) __bf16 bf16x8;

#define DEV static __device__ __forceinline__

// ---------- helpers ----------
DEV float b2f(u16 v) { return __uint_as_float(((unsigned)v) << 16); }

DEV u16 f2b(float f) {  // round-to-nearest-even f32 -> bf16 bits
  unsigned u = __float_as_uint(f);
  return (u16)((u + 0x7fffu + ((u >> 16) & 1u)) >> 16);
}

DEV unsigned pk2(float a, float b) {
  return (unsigned)f2b(a) | ((unsigned)f2b(b) << 16);
}

DEV void gload16(const void* g, void* l) {
  // async global->LDS, 16B per lane; LDS dest is wave-uniform base + lane*16
  __builtin_amdgcn_global_load_lds(
      (__attribute__((address_space(1))) void*)g,
      (__attribute__((address_space(3))) void*)l, 16, 0, 0);
}

DEV float wave_sum(float v) {
  #pragma unroll
  for (int o = 32; o; o >>= 1) v += __shfl_xor(v, o, 64);
  return v;
}

// ---------- embeddings + LayerNorm (bf16 out) ----------
__global__ __launch_bounds__(256)
void embed_ln_k(const int* __restrict__ ids, const int* __restrict__ tts,
                const float* __restrict__ we, const float* __restrict__ pe,
                const float* __restrict__ te, const float* __restrict__ g,
                const float* __restrict__ bb, u16* __restrict__ x) {
  const int t = blockIdx.x;          // 0..4095 token index
  const int pos = t & 511;
  const int tid = threadIdx.x, lane = tid & 63, w = tid >> 6;
  const int id = ids[t], tt = tts[t];
  __shared__ float red[8];
  float e[3];
  #pragma unroll
  for (int k = 0; k < 3; k++) {
    int d = tid + k * 256;
    e[k] = we[(size_t)id * 768 + d] + pe[(size_t)pos * 768 + d] + te[(size_t)tt * 768 + d];
  }
  float s = wave_sum(e[0] + e[1] + e[2]);
  if (lane == 0) red[w] = s;
  __syncthreads();
  const float mean = (red[0] + red[1] + red[2] + red[3]) * (1.f / 768.f);
  float v2 = 0.f;
  #pragma unroll
  for (int k = 0; k < 3; k++) { float d = e[k] - mean; v2 += d * d; }
  v2 = wave_sum(v2);
  if (lane == 0) red[4 + w] = v2;
  __syncthreads();
  const float var = (red[4] + red[5] + red[6] + red[7]) * (1.f / 768.f);
  const float rstd = rsqrtf(var + 1e-5f);
  #pragma unroll
  for (int k = 0; k < 3; k++) {
    int d = tid + k * 256;
    x[(size_t)t * 768 + d] = f2b((e[k] - mean) * rstd * g[d] + bb[d]);
  }
}

// ---------- LayerNorm bf16 -> bf16, wave-per-token (no LDS, no barriers) ----------
// grid 1024 blocks x 256 threads = 4096 tokens; uint2 loads (4 bf16), f32 stats.
__global__ __launch_bounds__(256)
void ln_k(const u16* __restrict__ xin, const float* __restrict__ g,
          const float* __restrict__ bb, u16* __restrict__ out) {
  const int lane = threadIdx.x & 63, w = threadIdx.x >> 6;
  const int t = blockIdx.x * 4 + w;
  const uint2* x2 = (const uint2*)(xin + (size_t)t * 768);
  float e[12];
  #pragma unroll
  for (int k = 0; k < 3; k++) {
    uint2 v = x2[k * 64 + lane];
    e[k * 4 + 0] = b2f((u16)v.x);
    e[k * 4 + 1] = b2f((u16)(v.x >> 16));
    e[k * 4 + 2] = b2f((u16)v.y);
    e[k * 4 + 3] = b2f((u16)(v.y >> 16));
  }
  float s = 0.f;
  #pragma unroll
  for (int i = 0; i < 12; i++) s += e[i];
  s = wave_sum(s);
  const float mean = s * (1.f / 768.f);
  float v2 = 0.f;
  #pragma unroll
  for (int i = 0; i < 12; i++) { float d = e[i] - mean; v2 += d * d; }
  v2 = wave_sum(v2);
  const float rstd = rsqrtf(v2 * (1.f / 768.f) + 1e-5f);
  uint2* o2 = (uint2*)(out + (size_t)t * 768);
  #pragma unroll
  for (int k = 0; k < 3; k++) {
    float4 gv = ((const float4*)g)[k * 64 + lane];
    float4 bv = ((const float4*)bb)[k * 64 + lane];
    uint2 o;
    o.x = pk2((e[k * 4 + 0] - mean) * rstd * gv.x + bv.x,
              (e[k * 4 + 1] - mean) * rstd * gv.y + bv.y);
    o.y = pk2((e[k * 4 + 2] - mean) * rstd * gv.z + bv.z,
              (e[k * 4 + 3] - mean) * rstd * gv.w + bv.w);
    o2[k * 64 + lane] = o;
  }
}

// ---------- word_emb f32[30522,768] -> bf16[30592,768], pad rows zeroed ----------
__global__ __launch_bounds__(256)
void wecast_k(const float* __restrict__ we, u16* __restrict__ out) {
  const int i = blockIdx.x * 256 + threadIdx.x;  // 8-elem chunk, 2,936,832 total
  const int row = i / 96, c8 = i % 96;
  uint2 o0 = make_uint2(0u, 0u), o1 = make_uint2(0u, 0u);
  if (row < 30522) {
    const float* src = we + (size_t)row * 768 + c8 * 8;
    float4 a = ((const float4*)src)[0];
    float4 b = ((const float4*)src)[1];
    o0.x = pk2(a.x, a.y); o0.y = pk2(a.z, a.w);
    o1.x = pk2(b.x, b.y); o1.y = pk2(b.z, b.w);
  }
  uint2* dst = (uint2*)(out + (size_t)i * 8);
  dst[0] = o0;
  dst[1] = o1;
}

// ---------- transpose-convert tile body: W f32[K,N] 64x64 tile -> Wt bf16[N,K] ----------
DEV void tconv_tile(const float* __restrict__ W, u16* __restrict__ Wt,
                    int K, int N, int n0, int k0, int tid, u16 (*t)[65]) {
  const int kl = tid >> 4, nl4 = (tid & 15) * 4;
  #pragma unroll
  for (int i = 0; i < 4; i++) {
    float4 v = *(const float4*)(W + (size_t)(k0 + kl + i * 16) * N + n0 + nl4);
    t[nl4 + 0][kl + i * 16] = f2b(v.x);
    t[nl4 + 1][kl + i * 16] = f2b(v.y);
    t[nl4 + 2][kl + i * 16] = f2b(v.z);
    t[nl4 + 3][kl + i * 16] = f2b(v.w);
  }
  __syncthreads();
  const int nl = tid >> 2, kc = (tid & 3) * 16;
  unsigned wd[8];
  #pragma unroll
  for (int j = 0; j < 8; j++)
    wd[j] = (unsigned)t[nl][kc + 2 * j] | ((unsigned)t[nl][kc + 2 * j + 1] << 16);
  int4* dst = (int4*)(Wt + (size_t)(n0 + nl) * K + k0 + kc);
  dst[0] = make_int4((int)wd[0], (int)wd[1], (int)wd[2], (int)wd[3]);
  dst[1] = make_int4((int)wd[4], (int)wd[5], (int)wd[6], (int)wd[7]);
}

// per-layer fallback kernel: grid (N/64, K/64)
__global__ __launch_bounds__(256)
void tconv_k(const float* __restrict__ W, u16* __restrict__ Wt, int K, int N) {
  __shared__ u16 t[64][65];
  tconv_tile(W, Wt, K, N, blockIdx.x * 64, blockIdx.y * 64, threadIdx.x, t);
}

// all layers, all 4 weight matrices, one launch. 1728 tiles/layer x 12.
__global__ __launch_bounds__(256)
void tconv_all_k(const float* __restrict__ wqkv, const float* __restrict__ wprj,
                 const float* __restrict__ wfc, const float* __restrict__ wfc2,
                 u16* __restrict__ wall) {
  __shared__ u16 ts[64][65];
  const int tile = blockIdx.x;
  const int l = tile / 1728, t = tile % 1728;
  u16* base = wall + (size_t)l * 7077888;
  const float* W; u16* Wt; int K, N, loc;
  if (t < 432)       { W = wqkv + (size_t)l * 768 * 2304; Wt = base;           K = 768;  N = 2304; loc = t; }
  else if (t < 576)  { W = wprj + (size_t)l * 768 * 768;  Wt = base + 1769472; K = 768;  N = 768;  loc = t - 432; }
  else if (t < 1152) { W = wfc  + (size_t)l * 768 * 3072; Wt = base + 2359296; K = 768;  N = 3072; loc = t - 576; }
  else               { W = wfc2 + (size_t)l * 3072 * 768; Wt = base + 4718592; K = 3072; N = 768;  loc = t - 1152; }
  const int nbl = N >> 6;
  tconv_tile(W, Wt, K, N, (loc % nbl) * 64, (loc / nbl) * 64, threadIdx.x, ts);
}

// ---------- GEMM 128x128 (proven best): BK=64, single-buffered ----------
// LDS tiles [row][64] (128B rows) XOR-swizzled: 16B slot s of row r holds
// global slot s^(r&7); staged via pre-swizzled global_load_lds source ->
// conflict-free ds_read_b128. XCD-chunk swizzle, N-fastest decode.
// EPI: 0 = bf16; 1 = GELU -> bf16; 2 = resid_bf16 + v -> bf16.
template <int EPI>
__global__ __launch_bounds__(256)
void gemm_k(const u16* __restrict__ A, const u16* __restrict__ B,
            const float* __restrict__ bias, const u16* __restrict__ resid,
            void* __restrict__ Cptr, int Ndim, int Kdim, int Nblk) {
  __shared__ __align__(16) u16 As[128 * 64];
  __shared__ __align__(16) u16 Bs[128 * 64];
  const int tid = threadIdx.x, lane = tid & 63, w = tid >> 6;
  const int wr = w >> 1, wc = w & 1, fr = lane & 15, fq = lane >> 4;

  const int nwg = gridDim.x, chunk = nwg >> 3;
  const int tile = (blockIdx.x & 7) * chunk + (blockIdx.x >> 3);
  const int nb = tile % Nblk, mb = tile / Nblk;
  const int n0 = nb * 128, m0 = mb * 128;

  f32x4 acc[4][4] = {};
  const int rl = lane >> 3;                 // row-in-group 0..7
  const int sl = ((lane & 7) ^ rl) * 8;     // pre-swizzled k-slot (u16 units)

  for (int k0 = 0; k0 < Kdim; k0 += 64) {
    #pragma unroll
    for (int i = 0; i < 4; i++) {
      const int row = i * 32 + w * 8 + rl;
      gload16(A + (size_t)(m0 + row) * Kdim + k0 + sl, As + (i * 32 + w * 8) * 64);
      gload16(B + (size_t)(n0 + row) * Kdim + k0 + sl, Bs + (i * 32 + w * 8) * 64);
    }
    __syncthreads();
    #pragma unroll
    for (int kh = 0; kh < 2; kh++) {
      const int ks = ((kh * 4 + fq) ^ (fr & 7)) * 8;
      bf16x8 af[4], bfv[4];
      #pragma unroll
      for (int m = 0; m < 4; m++)
        af[m] = *(const bf16x8*)(&As[(wr * 64 + m * 16 + fr) * 64 + ks]);
      #pragma unroll
      for (int n = 0; n < 4; n++)
        bfv[n] = *(const bf16x8*)(&Bs[(wc * 64 + n * 16 + fr) * 64 + ks]);
      #pragma unroll
      for (int m = 0; m < 4; m++)
        #pragma unroll
        for (int n = 0; n < 4; n++)
          acc[m][n] = __builtin_amdgcn_mfma_f32_16x16x32_bf16(af[m], bfv[n], acc[m][n], 0, 0, 0);
    }
    __syncthreads();
  }

  #pragma unroll
  for (int m = 0; m < 4; m++) {
    const int row = m0 + wr * 64 + m * 16 + fq * 4;
    #pragma unroll
    for (int n = 0; n < 4; n++) {
      const int col = n0 + wc * 64 + n * 16 + fr;
      const float bv = (bias != nullptr) ? bias[col] : 0.f;
      #pragma unroll
      for (int r = 0; r < 4; r++) {
        float v = acc[m][n][r] + bv;
        const size_t idx = (size_t)(row + r) * Ndim + col;
        if (EPI == 0) {
          ((u16*)Cptr)[idx] = f2b(v);
        } else if (EPI == 1) {
          float t = v;
          float gl = 0.5f * t * (1.f + tanhf(0.7978845608f * (t + 0.044715f * t * t * t)));
          ((u16*)Cptr)[idx] = f2b(gl);
        } else if (EPI == 2) {
          ((u16*)Cptr)[idx] = f2b(b2f(resid[idx]) + v);
        }
      }
    }
  }
}

// ---------- GEMM 64x64 (proj, fc2; proven best): BK=64, single-buffered ----------
template <int EPI>
__global__ __launch_bounds__(256)
void gemm64_k(const u16* __restrict__ A, const u16* __restrict__ B,
              const float* __restrict__ bias, const u16* __restrict__ resid,
              void* __restrict__ Cptr, int Ndim, int Kdim, int Nblk) {
  __shared__ __align__(16) u16 As[64 * 64];
  __shared__ __align__(16) u16 Bs[64 * 64];
  const int tid = threadIdx.x, lane = tid & 63, w = tid >> 6;
  const int wr = w >> 1, wc = w & 1, fr = lane & 15, fq = lane >> 4;

  const int nwg = gridDim.x, chunk = nwg >> 3;
  const int tile = (blockIdx.x & 7) * chunk + (blockIdx.x >> 3);
  const int nb = tile % Nblk, mb = tile / Nblk;
  const int n0 = nb * 64, m0 = mb * 64;

  f32x4 acc[2][2] = {};
  const int rl = lane >> 3;
  const int sl = ((lane & 7) ^ rl) * 8;

  for (int k0 = 0; k0 < Kdim; k0 += 64) {
    #pragma unroll
    for (int i = 0; i < 2; i++) {
      const int row = i * 32 + w * 8 + rl;
      gload16(A + (size_t)(m0 + row) * Kdim + k0 + sl, As + (i * 32 + w * 8) * 64);
      gload16(B + (size_t)(n0 + row) * Kdim + k0 + sl, Bs + (i * 32 + w * 8) * 64);
    }
    __syncthreads();
    #pragma unroll
    for (int kh = 0; kh < 2; kh++) {
      const int ks = ((kh * 4 + fq) ^ (fr & 7)) * 8;
      bf16x8 af[2], bfv[2];
      #pragma unroll
      for (int m = 0; m < 2; m++)
        af[m] = *(const bf16x8*)(&As[(wr * 32 + m * 16 + fr) * 64 + ks]);
      #pragma unroll
      for (int n = 0; n < 2; n++)
        bfv[n] = *(const bf16x8*)(&Bs[(wc * 32 + n * 16 + fr) * 64 + ks]);
      #pragma unroll
      for (int m = 0; m < 2; m++)
        #pragma unroll
        for (int n = 0; n < 2; n++)
          acc[m][n] = __builtin_amdgcn_mfma_f32_16x16x32_bf16(af[m], bfv[n], acc[m][n], 0, 0, 0);
    }
    __syncthreads();
  }

  #pragma unroll
  for (int m = 0; m < 2; m++) {
    const int row = m0 + wr * 32 + m * 16 + fq * 4;
    #pragma unroll
    for (int n = 0; n < 2; n++) {
      const int col = n0 + wc * 32 + n * 16 + fr;
      const float bv = (bias != nullptr) ? bias[col] : 0.f;
      #pragma unroll
      for (int r = 0; r < 4; r++) {
        float v = acc[m][n][r] + bv;
        const size_t idx = (size_t)(row + r) * Ndim + col;
        if (EPI == 0) {
          ((u16*)Cptr)[idx] = f2b(v);
        } else if (EPI == 1) {
          float t = v;
          float gl = 0.5f * t * (1.f + tanhf(0.7978845608f * (t + 0.044715f * t * t * t)));
          ((u16*)Cptr)[idx] = f2b(gl);
        } else if (EPI == 2) {
          ((u16*)Cptr)[idx] = f2b(b2f(resid[idx]) + v);
        }
      }
    }
  }
}

// ---------- GEMM 256x128 (logits): BK=32 dbuf + counted vmcnt (T4) ----------
// Pipeline per K-tile: STAGE(next, 6 loads/wave) -> s_waitcnt vmcnt(6)
// (current tile's 6 loads done; next 6 stay in flight) -> s_barrier ->
// compute (32 MFMA/wave) -> s_barrier. Never drains vmcnt to 0 mid-loop.
// Regular cached stores: nt stores regressed (r14: WRITE 512->935 MB, partial
// -line writebacks; the strided f32 epilogue depends on L2 write coalescing).
// Swizzle: LDS slot s of row r holds global slot s^((r>>1)&3) -> conflict-free.
__global__ __launch_bounds__(256)
void gemm256_k(const u16* __restrict__ A, const u16* __restrict__ B,
               float* __restrict__ Cptr, int Ndim, int Kdim, int Nblk) {
  __shared__ __align__(16) u16 As[2][256 * 32];  // 2 x 16 KB
  __shared__ __align__(16) u16 Bs[2][128 * 32];  // 2 x 8 KB
  const int tid = threadIdx.x, lane = tid & 63, w = tid >> 6;
  const int fr = lane & 15, fq = lane >> 4;

  const int nwg = gridDim.x, chunk = nwg >> 3;
  const int tile = (blockIdx.x & 7) * chunk + (blockIdx.x >> 3);
  const int nb = tile % Nblk, mb = tile / Nblk;
  const int n0 = nb * 128, m0 = mb * 256;

  f32x4 acc[4][8] = {};
  const int rq = lane >> 2;                          // row within 16-row stripe
  const int sl = ((lane & 3) ^ ((lane >> 3) & 3)) * 8;

  #define STAGE256(k0, buf)                                                     \
    {                                                                           \
      _Pragma("unroll")                                                         \
      for (int i = 0; i < 4; i++) {                                             \
        const int st = i * 4 + w;                                               \
        gload16(A + (size_t)(m0 + st * 16 + rq) * Kdim + (k0) + sl,             \
                &As[buf][st * 512]);                                            \
      }                                                                         \
      _Pragma("unroll")                                                         \
      for (int i = 0; i < 2; i++) {                                             \
        const int st = i * 4 + w;                                               \
        gload16(B + (size_t)(n0 + st * 16 + rq) * Kdim + (k0) + sl,             \
                &Bs[buf][st * 512]);                                            \
      }                                                                         \
    }

  STAGE256(0, 0);
  int buf = 0;
  const int nt = Kdim >> 5;

  for (int t = 0; t < nt; ++t) {
    if (t + 1 < nt) {
      STAGE256((t + 1) * 32, buf ^ 1);
      asm volatile("s_waitcnt vmcnt(6)" ::: "memory");
    } else {
      asm volatile("s_waitcnt vmcnt(0)" ::: "memory");
    }
    __builtin_amdgcn_s_barrier();
    __builtin_amdgcn_sched_barrier(0);

    const int ks = (fq ^ ((fr >> 1) & 3)) * 8;
    bf16x8 af[4], bfv[8];
    #pragma unroll
    for (int m = 0; m < 4; m++)
      af[m] = *(const bf16x8*)(&As[buf][(w * 64 + m * 16 + fr) * 32 + ks]);
    #pragma unroll
    for (int n = 0; n < 8; n++)
      bfv[n] = *(const bf16x8*)(&Bs[buf][(n * 16 + fr) * 32 + ks]);
    #pragma unroll
    for (int m = 0; m < 4; m++)
      #pragma unroll
      for (int n = 0; n < 8; n++)
        acc[m][n] = __builtin_amdgcn_mfma_f32_16x16x32_bf16(af[m], bfv[n], acc[m][n], 0, 0, 0);

    __builtin_amdgcn_sched_barrier(0);
    __builtin_amdgcn_s_barrier();
    buf ^= 1;
  }
  #undef STAGE256

  #pragma unroll
  for (int m = 0; m < 4; m++) {
    const int row = m0 + w * 64 + m * 16 + fq * 4;
    #pragma unroll
    for (int n = 0; n < 8; n++) {
      const int col = n0 + n * 16 + fr;
      if (col >= Ndim) continue;
      #pragma unroll
      for (int r = 0; r < 4; r++)
        Cptr[(size_t)(row + r) * Ndim + col] = acc[m][n][r];
    }
  }
}

// ---------- MFMA flash attention, swapped-QK^T lane-local softmax ----------
__global__ __launch_bounds__(256)
void attn_mfma_k(const u16* __restrict__ qkv, const float* __restrict__ amask,
                 u16* __restrict__ y) {
  __shared__ __align__(16) u16 Ks[2][64 * 64];   // [key][dim]  16 KB
  __shared__ __align__(16) u16 Vt[2][64 * 64];   // [dim][key]  16 KB
  __shared__ __align__(16) u16 Ps[4][16 * 64];   // per-wave P^T[q][key] 8 KB
  __shared__ float bias_lds[512];                // (1-mask)*-1e4  2 KB
  const int tid = threadIdx.x, lane = tid & 63, w = tid >> 6;
  const int bh = blockIdx.y, b = bh / 12, hh = bh % 12;
  const int q0 = blockIdx.x * 64;
  const u16* qb = qkv + (size_t)(b * 512) * 2304 + hh * 64;
  const u16* kb = qb + 768;
  const u16* vb = qb + 1536;
  const int fr = lane & 15, fq = lane >> 4;

  // mask bias -> LDS once
  bias_lds[tid] = (1.0f - amask[b * 512 + tid]) * -10000.0f;
  bias_lds[tid + 256] = (1.0f - amask[b * 512 + tid + 256]) * -10000.0f;

  // Q fragments (B-operand: lane fr -> q col fr)
  bf16x8 af[2];
  {
    const u16* qrow = qb + (size_t)(q0 + w * 16 + fr) * 2304;
    af[0] = *(const bf16x8*)(qrow + fq * 8);
    af[1] = *(const bf16x8*)(qrow + 32 + fq * 8);
  }

  auto stageK = [&](int kt, int nb) {
    const int r0 = lane >> 3, dc = lane & 7, s = dc ^ r0;
    #pragma unroll
    for (int p = 0; p < 2; p++) {
      const int i = w * 2 + p;
      gload16(kb + (size_t)(kt * 64 + i * 8 + r0) * 2304 + s * 8,
              (void*)&Ks[nb][i * 512]);
    }
  };
  auto stageV = [&](int kt, int nb) {
    #pragma unroll
    for (int p = 0; p < 2; p++) {
      const int dc = w * 2 + p;
      int4 vd = *(const int4*)(vb + (size_t)(kt * 64 + lane) * 2304 + dc * 8);
      union { int4 v; u16 e[8]; } u; u.v = vd;
      #pragma unroll
      for (int ii = 0; ii < 8; ii++)
        Vt[nb][(dc * 8 + ii) * 64 + (lane ^ (ii << 3))] = u.e[ii];
    }
  };

  f32x4 O[4];   // O^T: lane holds O[d = nd*16 + fq*4 + r][q = fr]
  #pragma unroll
  for (int nd = 0; nd < 4; nd++) O[nd] = f32x4{0.f, 0.f, 0.f, 0.f};
  float run_m = -3.0e38f, run_l = 0.f;

  stageK(0, 0); stageV(0, 0);
  __syncthreads();
  int cur = 0;

  for (int kt = 0; kt < 8; kt++) {
    if (kt < 7) { stageK(kt + 1, cur ^ 1); stageV(kt + 1, cur ^ 1); }

    // ---- QK^T swapped: sacc[n] = mfma(K-frag as A, Q-frag as B) ----
    f32x4 sacc[4];
    #pragma unroll
    for (int n = 0; n < 4; n++) sacc[n] = f32x4{0.f, 0.f, 0.f, 0.f};
    __builtin_amdgcn_s_setprio(1);
    #pragma unroll
    for (int n = 0; n < 4; n++)
      #pragma unroll
      for (int kh = 0; kh < 2; kh++) {
        bf16x8 kf = *(const bf16x8*)(&Ks[cur][(n * 16 + fr) * 64 + ((kh * 4 + fq) ^ (fr & 7)) * 8]);
        sacc[n] = __builtin_amdgcn_mfma_f32_16x16x32_bf16(kf, af[kh], sacc[n], 0, 0, 0);
      }
    __builtin_amdgcn_s_setprio(0);

    // ---- lane-local softmax: 16 scores for q=fr (keys n*16+fq*4+r) ----
    float s[4][4];
    float vm = -3.0e38f;
    #pragma unroll
    for (int n = 0; n < 4; n++) {
      float4 b4 = *(const float4*)(&bias_lds[kt * 64 + n * 16 + fq * 4]);
      s[n][0] = sacc[n][0] * 0.125f + b4.x;
      s[n][1] = sacc[n][1] * 0.125f + b4.y;
      s[n][2] = sacc[n][2] * 0.125f + b4.z;
      s[n][3] = sacc[n][3] * 0.125f + b4.w;
      vm = fmaxf(vm, fmaxf(fmaxf(s[n][0], s[n][1]), fmaxf(s[n][2], s[n][3])));
    }
    vm = fmaxf(vm, __shfl_xor(vm, 16, 64));
    vm = fmaxf(vm, __shfl_xor(vm, 32, 64));
    const float nm = fmaxf(run_m, vm);
    const float al = __expf(run_m - nm);
    run_m = nm;
    float p[4][4], ts = 0.f;
    #pragma unroll
    for (int n = 0; n < 4; n++)
      #pragma unroll
      for (int r = 0; r < 4; r++) { p[n][r] = __expf(s[n][r] - nm); ts += p[n][r]; }
    ts += __shfl_xor(ts, 16, 64);
    ts += __shfl_xor(ts, 32, 64);
    run_l = run_l * al + ts;
    #pragma unroll
    for (int nd = 0; nd < 4; nd++) O[nd] *= al;

    // ---- P^T[q=fr][key] -> Ps (swizzled 16B slots within 128B rows) ----
    #pragma unroll
    for (int n = 0; n < 4; n++) {
      uint2 dw;
      dw.x = pk2(p[n][0], p[n][1]);
      dw.y = pk2(p[n][2], p[n][3]);
      const int slot = (2 * n + (fq >> 1)) ^ (fr & 7);
      *(uint2*)((char*)&Ps[w][0] + fr * 128 + slot * 16 + (fq & 1) * 8) = dw;
    }
    asm volatile("s_waitcnt lgkmcnt(0)" ::: "memory");
    __builtin_amdgcn_sched_barrier(0);

    // ---- PV: O^T[d][q] += V^T-frag (A, rows=d) x P^T-frag (B, cols=q) ----
    bf16x8 pb[2];
    #pragma unroll
    for (int kh = 0; kh < 2; kh++)
      pb[kh] = *(const bf16x8*)((char*)&Ps[w][0] + fr * 128 + (((kh * 4 + fq) ^ (fr & 7)) * 16));
    __builtin_amdgcn_s_setprio(1);
    #pragma unroll
    for (int nd = 0; nd < 4; nd++) {
      bf16x8 vf0 = *(const bf16x8*)(&Vt[cur][(nd * 16 + fr) * 64 + ((0 + fq) ^ (fr & 7)) * 8]);
      bf16x8 vf1 = *(const bf16x8*)(&Vt[cur][(nd * 16 + fr) * 64 + ((4 + fq) ^ (fr & 7)) * 8]);
      O[nd] = __builtin_amdgcn_mfma_f32_16x16x32_bf16(vf0, pb[0], O[nd], 0, 0, 0);
      O[nd] = __builtin_amdgcn_mfma_f32_16x16x32_bf16(vf1, pb[1], O[nd], 0, 0, 0);
    }
    __builtin_amdgcn_s_setprio(0);
    __syncthreads();
    cur ^= 1;
  }

  // ---- epilogue: lane writes q=fr row, d = nd*16 + fq*4 + {0..3} packed ----
  const float inv = 1.0f / run_l;
  u16* yrow = y + (size_t)(b * 512 + q0 + w * 16 + fr) * 768 + hh * 64;
  #pragma unroll
  for (int nd = 0; nd < 4; nd++) {
    uint2 o;
    o.x = pk2(O[nd][0] * inv, O[nd][1] * inv);
    o.y = pk2(O[nd][2] * inv, O[nd][3] * inv);
    *(uint2*)(yrow + nd * 16 + fq * 4) = o;
  }
}

// ---------- launch ----------
extern "C" void kernel_launch(void* const* d_in, const int* in_sizes, int n_in,
                              void* d_out, int out_size, void* d_ws, size_t ws_size,
                              hipStream_t stream) {
  (void)in_sizes; (void)n_in; (void)out_size;
  const int*   ids  = (const int*)d_in[0];
  const int*   tts  = (const int*)d_in[1];
  const float* am   = (const float*)d_in[2];
  const float* we   = (const float*)d_in[3];
  const float* pe   = (const float*)d_in[4];
  const float* te   = (const float*)d_in[5];
  const float* eg   = (const float*)d_in[6];
  const float* eb   = (const float*)d_in[7];
  const float* l1g  = (const float*)d_in[8];
  const float* l1b  = (const float*)d_in[9];
  const float* wqkv = (const float*)d_in[10];
  const float* bqkv = (const float*)d_in[11];
  const float* wprj = (const float*)d_in[12];
  const float* bprj = (const float*)d_in[13];
  const float* l2g  = (const float*)d_in[14];
  const float* l2b  = (const float*)d_in[15];
  const float* wfc  = (const float*)d_in[16];
  const float* bfc  = (const float*)d_in[17];
  const float* wfc2 = (const float*)d_in[18];
  const float* bfc2 = (const float*)d_in[19];

  char* ws = (char*)d_ws;
  u16*  x    = (u16*)ws;                        //  6,291,456 B  residual stream bf16
  u16*  h    = (u16*)(ws + 6291456);            //  6,291,456 B  LN output bf16
  u16*  qkv  = (u16*)(ws + 12582912);           // 18,874,368 B
  u16*  y    = (u16*)(ws + 31457280);           //  6,291,456 B
  u16*  fc   = (u16*)(ws + 12582912);           // aliases qkv+y (dead by then)
  u16*  we_b = (u16*)(ws + 37748736);           // 46,989,312 B  [30592,768] zero-padded
  u16*  wall = (u16*)(ws + 84738048);           // upfront: 169,869,312 B (12 x 14,155,776)
  // upfront total: 254,607,360 B; fallback total: 98,893,824 B
  const bool upfront = ws_size >= 254607360ull;
  // fallback per-layer staging buffers live where wall starts
  u16* wqkv_f = (u16*)(ws + 84738048);
  u16* wprj_f = wqkv_f + 1769472;
  u16* wfc_f  = wqkv_f + 2359296;
  u16* wfc2_f = wqkv_f + 4718592;

  wecast_k<<<11472, 256, 0, stream>>>(we, we_b);
  embed_ln_k<<<4096, 256, 0, stream>>>(ids, tts, we, pe, te, eg, eb, x);
  if (upfront)
    tconv_all_k<<<20736, 256, 0, stream>>>(wqkv, wprj, wfc, wfc2, wall);

  for (int l = 0; l < 12; l++) {
    u16 *wq_b, *wp_b, *wf_b, *w2_b;
    if (upfront) {
      u16* base = wall + (size_t)l * 7077888;
      wq_b = base; wp_b = base + 1769472; wf_b = base + 2359296; w2_b = base + 4718592;
    } else {
      tconv_k<<<dim3(36, 12), 256, 0, stream>>>(wqkv + (size_t)l * 768 * 2304, wqkv_f, 768, 2304);
      tconv_k<<<dim3(12, 12), 256, 0, stream>>>(wprj + (size_t)l * 768 * 768,  wprj_f, 768, 768);
      tconv_k<<<dim3(48, 12), 256, 0, stream>>>(wfc  + (size_t)l * 768 * 3072, wfc_f,  768, 3072);
      tconv_k<<<dim3(12, 48), 256, 0, stream>>>(wfc2 + (size_t)l * 3072 * 768, wfc2_f, 3072, 768);
      wq_b = wqkv_f; wp_b = wprj_f; wf_b = wfc_f; w2_b = wfc2_f;
    }

    ln_k<<<1024, 256, 0, stream>>>(x, l1g + l * 768, l1b + l * 768, h);
    gemm_k<0><<<576, 256, 0, stream>>>(
        h, wq_b, bqkv + l * 2304, nullptr, qkv, 2304, 768, 18);
    attn_mfma_k<<<dim3(8, 96), 256, 0, stream>>>(qkv, am, y);
    gemm64_k<2><<<768, 256, 0, stream>>>(
        y, wp_b, bprj + l * 768, x, x, 768, 768, 12);
    ln_k<<<1024, 256, 0, stream>>>(x, l2g + l * 768, l2b + l * 768, h);
    gemm_k<1><<<768, 256, 0, stream>>>(
        h, wf_b, bfc + l * 3072, nullptr, fc, 3072, 768, 24);
    gemm64_k<2><<<768, 256, 0, stream>>>(
        fc, w2_b, bfc2 + l * 768, x, x, 768, 3072, 12);
  }

  gemm256_k<<<3824, 256, 0, stream>>>(
      x, we_b, (float*)d_out, 30522, 768, 239);
}